// Round 3
// baseline (489.773 us; speedup 1.0000x reference)
//
#include <hip/hip_runtime.h>
#include <stdint.h>

#define G_HEADS 16
#define HDIM    64
#define DMODEL  1024
#define TSEQ    4096
#define BATCH   4
#define NROWS   (BATCH*TSEQ)   // 16384

typedef __bf16 bf16_t;
typedef bf16_t bf16x8 __attribute__((ext_vector_type(8)));
typedef float  f32x4  __attribute__((ext_vector_type(4)));
typedef float  f32x4e __attribute__((ext_vector_type(4)));
typedef unsigned short u16x4 __attribute__((ext_vector_type(4)));

__device__ __forceinline__ unsigned short bf16_rne(float f){
  uint32_t u = __float_as_uint(f);
  u += 0x7fffu + ((u >> 16) & 1u);
  return (unsigned short)(u >> 16);
}
__device__ __forceinline__ float elu1(float x){ return x > 0.f ? x + 1.f : __expf(x); }

#define AS1 __attribute__((address_space(1)))
#define AS3 __attribute__((address_space(3)))
__device__ __forceinline__ void gl_lds16(const void* g, void* l){
  __builtin_amdgcn_global_load_lds((const AS1 void*)g, (AS3 void*)l, 16, 0, 0);
}

__device__ __forceinline__ f32x4 mfma16(bf16x8 a, bf16x8 b, f32x4 c){
  return __builtin_amdgcn_mfma_f32_16x16x32_bf16(a, b, c, 0, 0, 0);
}

// ---------------------------------------------------------------- convert
struct CvtArgs {
  const float* src[7];
  unsigned short* dst[7];
  int n4[7];
};

__global__ void cvt_bf16(CvtArgs a){
  int j = blockIdx.y;
  const f32x4e* s = (const f32x4e*)a.src[j];
  u16x4* d = (u16x4*)a.dst[j];
  int n4 = a.n4[j];
  for (int i = blockIdx.x*blockDim.x + threadIdx.x; i < n4; i += gridDim.x*blockDim.x){
    f32x4e v = s[i];
    u16x4 o;
    o[0] = bf16_rne(v[0]); o[1] = bf16_rne(v[1]);
    o[2] = bf16_rne(v[2]); o[3] = bf16_rne(v[3]);
    d[i] = o;
  }
}

// ---------------------------------------------------------------- GEMM (B^T form), m97 structure
// mode 0: qf = elu1(q@Wq.T+bq)            -> natural [row][col] bf16
// mode 1: kfT = mask*elu1(k@Wk.T+bk)      -> transposed [(b*1024+col)][t] bf16
// mode 2: vpT = v@Wv.T+bv                 -> transposed bf16
// mode 3: out = o@Wo.T+bo                 -> natural f32
struct ProjArgs {
  const unsigned short* X[4];
  const unsigned short* Wt[4];
  const float* bias[4];
  const int* mask;
  unsigned short* outB[3];
  float* outF;
  int mode_base;
};

__global__ __launch_bounds__(256) void gemm_bt(ProjArgs args)
{
  int mode = args.mode_base + blockIdx.z;
  const unsigned short* X = args.X[mode];
  const unsigned short* W = args.Wt[mode];
  const float* bias = args.bias[mode];
  int tm = blockIdx.x & 127, tn = blockIdx.x >> 7;
  int row0 = tm * 128, col0 = tn * 128;
  int tid = threadIdx.x, lane = tid & 63, wid = tid >> 6;
  int wm = wid & 1, wn = wid >> 1;
  __shared__ __align__(16) unsigned short Al[128*32];
  __shared__ __align__(16) unsigned short Bl[128*32];
  int sr = tid >> 2, sc = (tid & 3) * 8;
  const unsigned short* ga = X + (size_t)(row0 + sr)*DMODEL + sc;
  const unsigned short* gb = W + (size_t)(col0 + sr)*DMODEL + sc;
  char* lA = (char*)Al + wid*1024;
  char* lB = (char*)Bl + wid*1024;
  f32x4 acc[4][4] = {};
  int fr = lane & 15, fg = lane >> 4;
  for (int kt = 0; kt < DMODEL; kt += 32){
    gl_lds16(ga + kt,               lA);
    gl_lds16(ga + 64*DMODEL + kt,   lA + 4096);
    gl_lds16(gb + kt,               lB);
    gl_lds16(gb + 64*DMODEL + kt,   lB + 4096);
    __syncthreads();
    bf16x8 af[4], bfr[4];
    #pragma unroll
    for (int mi=0; mi<4; mi++) af[mi]  = *(const bf16x8*)&Al[(wm*64 + mi*16 + fr)*32 + fg*8];
    #pragma unroll
    for (int ni=0; ni<4; ni++) bfr[ni] = *(const bf16x8*)&Bl[(wn*64 + ni*16 + fr)*32 + fg*8];
    #pragma unroll
    for (int mi=0; mi<4; mi++)
      #pragma unroll
      for (int ni=0; ni<4; ni++)
        acc[mi][ni] = mfma16(af[mi], bfr[ni], acc[mi][ni]);
    __syncthreads();
  }
  // epilogue: C layout col=lane&15, row=(lane>>4)*4+reg [m89-verified]
  float bb[4];
  #pragma unroll
  for (int ni=0; ni<4; ni++) bb[ni] = bias[col0 + wn*64 + ni*16 + fr];

  if (mode == 3){
    float* O = args.outF;
    #pragma unroll
    for (int mi=0; mi<4; mi++){
      int gr = row0 + wm*64 + mi*16 + fg*4;
      #pragma unroll
      for (int ni=0; ni<4; ni++){
        int gc = col0 + wn*64 + ni*16 + fr;
        #pragma unroll
        for (int rr=0; rr<4; rr++)
          O[(size_t)(gr+rr)*DMODEL + gc] = acc[mi][ni][rr] + bb[ni];
      }
    }
  } else if (mode == 0){
    unsigned short* O = args.outB[0];
    #pragma unroll
    for (int mi=0; mi<4; mi++){
      int gr = row0 + wm*64 + mi*16 + fg*4;
      #pragma unroll
      for (int ni=0; ni<4; ni++){
        int gc = col0 + wn*64 + ni*16 + fr;
        #pragma unroll
        for (int rr=0; rr<4; rr++){
          float v = elu1(acc[mi][ni][rr] + bb[ni]);
          O[(size_t)(gr+rr)*DMODEL + gc] = bf16_rne(v);
        }
      }
    }
  } else {
    unsigned short* O = args.outB[mode];
    #pragma unroll
    for (int mi=0; mi<4; mi++){
      int gr = row0 + wm*64 + mi*16 + fg*4;
      int b_ = gr >> 12, t_ = gr & (TSEQ-1);
      int mk[4];
      #pragma unroll
      for (int rr=0; rr<4; rr++) mk[rr] = (mode==1) ? args.mask[gr+rr] : 1;
      #pragma unroll
      for (int ni=0; ni<4; ni++){
        int gc = col0 + wn*64 + ni*16 + fr;
        u16x4 st;
        #pragma unroll
        for (int rr=0; rr<4; rr++){
          float v = acc[mi][ni][rr] + bb[ni];
          if (mode==1){ v = elu1(v); if (mk[rr] == 0) v = 0.f; }
          st[rr] = bf16_rne(v);
        }
        *(u16x4*)&O[((size_t)((b_<<10) + gc))*TSEQ + t_] = st;
      }
    }
  }
}

// ---------------------------------------------------------------- per-head K^T V reduction + k_sum
__global__ void kv_reduce(const unsigned short* __restrict__ kfT,
                          const unsigned short* __restrict__ vpT,
                          float* __restrict__ kv, float* __restrict__ ksum)
{
  int bg = blockIdx.x;         // 0..63 = b*16+g
  int chunk = blockIdx.y;      // 0..3, 1024 t each
  int tid = threadIdx.x, lane = tid & 63, wid = tid >> 6;
  int fr = lane & 15, fg = lane >> 4;
  const unsigned short* A  = kfT + (size_t)bg*HDIM*TSEQ;
  const unsigned short* Bv = vpT + (size_t)bg*HDIM*TSEQ;
  int t0 = chunk*1024 + wid*256;
  f32x4 acc[4][4] = {};
  float ksp[4] = {0.f,0.f,0.f,0.f};
  for (int ks = 0; ks < 256; ks += 32){
    int tc = t0 + ks + fg*8;
    bf16x8 af[4], bfr[4];
    #pragma unroll
    for (int mi=0; mi<4; mi++) af[mi]  = *(const bf16x8*)&A[(size_t)(mi*16+fr)*TSEQ + tc];
    #pragma unroll
    for (int ni=0; ni<4; ni++) bfr[ni] = *(const bf16x8*)&Bv[(size_t)(ni*16+fr)*TSEQ + tc];
    #pragma unroll
    for (int mi=0; mi<4; mi++){
      float s = 0.f;
      #pragma unroll
      for (int j=0;j<8;j++) s += (float)af[mi][j];
      ksp[mi] += s;
    }
    #pragma unroll
    for (int mi=0; mi<4; mi++)
      #pragma unroll
      for (int ni=0; ni<4; ni++)
        acc[mi][ni] = mfma16(af[mi], bfr[ni], acc[mi][ni]);
  }
  #pragma unroll
  for (int mi=0; mi<4; mi++){
    float s2 = ksp[mi];
    s2 += __shfl_xor(s2, 16);
    s2 += __shfl_xor(s2, 32);
    if (lane < 16) atomicAdd(&ksum[bg*HDIM + mi*16 + lane], s2);
  }
  __shared__ float red[4][HDIM*HDIM];   // 64 KB
  #pragma unroll
  for (int mi=0; mi<4; mi++)
    #pragma unroll
    for (int ni=0; ni<4; ni++)
      #pragma unroll
      for (int rr=0; rr<4; rr++)
        red[wid][(mi*16+fg*4+rr)*HDIM + ni*16+fr] = acc[mi][ni][rr];
  __syncthreads();
  for (int i = tid; i < HDIM*HDIM; i += 256){
    float s = red[0][i] + red[1][i] + red[2][i] + red[3][i];
    atomicAdd(&kv[(size_t)bg*HDIM*HDIM + i], s);
  }
}

// ---------------------------------------------------------------- o = (qf . k_v) / (qf . k_sum)
__global__ void qkv_div(const unsigned short* __restrict__ qf,
                        const float* __restrict__ kv,
                        const float* __restrict__ ksum,
                        unsigned short* __restrict__ o_)
{
  int bg = blockIdx.x, mt = blockIdx.y;
  int b = bg >> 4, g = bg & 15;
  int tid = threadIdx.x, lane = tid & 63, wid = tid >> 6;
  __shared__ __align__(16) unsigned short kvT[HDIM*HDIM]; // bf16 [cv][ck]
  __shared__ float ksl[HDIM];
  __shared__ float den[4][64];
  for (int i = tid; i < HDIM*HDIM; i += 256){
    int ck = i >> 6, cv = i & 63;
    kvT[cv*HDIM + ck] = bf16_rne(kv[(size_t)bg*HDIM*HDIM + i]);
  }
  if (tid < HDIM) ksl[tid] = ksum[bg*HDIM + tid];
  __syncthreads();
  int fr = lane & 15, fg = lane >> 4;
  bf16x8 bfrag[2][4];
  #pragma unroll
  for (int ks2=0; ks2<2; ks2++)
    #pragma unroll
    for (int ni=0; ni<4; ni++)
      bfrag[ks2][ni] = *(const bf16x8*)&kvT[(ni*16+fr)*HDIM + ks2*32 + fg*8];
  int t0 = mt*256 + wid*64;
  const unsigned short* A = qf + ((size_t)b*TSEQ + t0)*DMODEL + g*HDIM;
  f32x4 acc[4][4] = {};
  float dp[4] = {0.f,0.f,0.f,0.f};
  #pragma unroll
  for (int ks2=0; ks2<2; ks2++){
    bf16x8 af[4];
    #pragma unroll
    for (int mi=0; mi<4; mi++) af[mi] = *(const bf16x8*)&A[(size_t)(mi*16+fr)*DMODEL + ks2*32 + fg*8];
    #pragma unroll
    for (int mi=0; mi<4; mi++){
      float s = 0.f;
      #pragma unroll
      for (int j=0;j<8;j++) s += (float)af[mi][j] * ksl[ks2*32 + fg*8 + j];
      dp[mi] += s;
    }
    #pragma unroll
    for (int mi=0; mi<4; mi++)
      #pragma unroll
      for (int ni=0; ni<4; ni++)
        acc[mi][ni] = mfma16(af[mi], bfrag[ks2][ni], acc[mi][ni]);
  }
  #pragma unroll
  for (int mi=0; mi<4; mi++){
    float s2 = dp[mi];
    s2 += __shfl_xor(s2, 16);
    s2 += __shfl_xor(s2, 32);
    if (lane < 16) den[wid][mi*16 + lane] = s2;
  }
  __syncthreads();
  unsigned short* O = o_ + ((size_t)b*TSEQ + t0)*DMODEL + g*HDIM;
  #pragma unroll
  for (int mi=0; mi<4; mi++)
    #pragma unroll
    for (int ni=0; ni<4; ni++)
      #pragma unroll
      for (int rr=0; rr<4; rr++){
        int lr = mi*16 + fg*4 + rr;
        float val = acc[mi][ni][rr] / den[wid][lr];
        O[(size_t)lr*DMODEL + ni*16 + fr] = bf16_rne(val);
      }
}

// ---------------------------------------------------------------- launch
extern "C" void kernel_launch(void* const* d_in, const int* in_sizes, int n_in,
                              void* d_out, int out_size, void* d_ws, size_t ws_size,
                              hipStream_t stream)
{
  const float* q  = (const float*)d_in[0];
  const float* k  = (const float*)d_in[1];
  const float* v  = (const float*)d_in[2];
  const int* mask = (const int*)d_in[3];
  const float* Wq = (const float*)d_in[4];
  const float* bq = (const float*)d_in[5];
  const float* Wk = (const float*)d_in[6];
  const float* bk = (const float*)d_in[7];
  const float* Wv = (const float*)d_in[8];
  const float* bv = (const float*)d_in[9];
  const float* Wo = (const float*)d_in[10];
  const float* bo = (const float*)d_in[11];
  float* out = (float*)d_out;

  char* w = (char*)d_ws;
  const size_t SZ_X = (size_t)NROWS*DMODEL*2;   // 32 MB
  const size_t SZ_W = (size_t)DMODEL*DMODEL*2;  // 2 MB
  unsigned short* Xq  = (unsigned short*)(w);
  unsigned short* Xk  = (unsigned short*)(w + 1*SZ_X);
  unsigned short* Xv  = (unsigned short*)(w + 2*SZ_X);
  unsigned short* qf  = (unsigned short*)(w + 3*SZ_X);
  unsigned short* kfT = (unsigned short*)(w + 4*SZ_X);
  unsigned short* vpT = (unsigned short*)(w + 5*SZ_X);
  unsigned short* o_  = Xq;  // alias: Xq is dead before qkv_div writes o_
  unsigned short* Wqb = (unsigned short*)(w + 6*SZ_X);
  unsigned short* Wkb = (unsigned short*)(w + 6*SZ_X + 1*SZ_W);
  unsigned short* Wvb = (unsigned short*)(w + 6*SZ_X + 2*SZ_W);
  unsigned short* Wob = (unsigned short*)(w + 6*SZ_X + 3*SZ_W);
  float* kv   = (float*)(w + 6*SZ_X + 4*SZ_W);
  float* ksum = (float*)(w + 6*SZ_X + 4*SZ_W + (size_t)64*HDIM*HDIM*4);

  hipMemsetAsync(kv, 0, (size_t)64*HDIM*HDIM*4 + 64*HDIM*4, stream);

  CvtArgs ca;
  ca.src[0]=q;  ca.dst[0]=Xq;  ca.n4[0]=NROWS*DMODEL/4;
  ca.src[1]=k;  ca.dst[1]=Xk;  ca.n4[1]=NROWS*DMODEL/4;
  ca.src[2]=v;  ca.dst[2]=Xv;  ca.n4[2]=NROWS*DMODEL/4;
  ca.src[3]=Wq; ca.dst[3]=Wqb; ca.n4[3]=DMODEL*DMODEL/4;
  ca.src[4]=Wk; ca.dst[4]=Wkb; ca.n4[4]=DMODEL*DMODEL/4;
  ca.src[5]=Wv; ca.dst[5]=Wvb; ca.n4[5]=DMODEL*DMODEL/4;
  ca.src[6]=Wo; ca.dst[6]=Wob; ca.n4[6]=DMODEL*DMODEL/4;
  cvt_bf16<<<dim3(4096,7), 256, 0, stream>>>(ca);

  ProjArgs pa;
  pa.X[0]=Xq;  pa.X[1]=Xk;  pa.X[2]=Xv;  pa.X[3]=o_;
  pa.Wt[0]=Wqb; pa.Wt[1]=Wkb; pa.Wt[2]=Wvb; pa.Wt[3]=Wob;
  pa.bias[0]=bq; pa.bias[1]=bk; pa.bias[2]=bv; pa.bias[3]=bo;
  pa.mask = mask;
  pa.outB[0]=qf; pa.outB[1]=kfT; pa.outB[2]=vpT;
  pa.outF = out;
  pa.mode_base = 0;
  gemm_bt<<<dim3(1024,1,3), 256, 0, stream>>>(pa);

  kv_reduce<<<dim3(64,4), 256, 0, stream>>>(kfT, vpT, kv, ksum);
  qkv_div<<<dim3(64,16), 256, 0, stream>>>(qf, kv, ksum, o_);

  ProjArgs pb = pa;
  pb.mode_base = 3;
  gemm_bt<<<dim3(1024,1,1), 256, 0, stream>>>(pb);
}